// Round 5
// baseline (689.408 us; speedup 1.0000x reference)
//
#include <hip/hip_runtime.h>
#include <hip/hip_bf16.h>
#include <stdint.h>

// DenseAttention: B=16, S=2048, D=256, fp32 in/out.
// d_out = [output (16*2048*256) | attn_weights (16*2048*2048)] fp32.
// Round 5 = Round 4 structure with 512-thread blocks (16 waves/CU, was 8).
// Two-kernel split, double-buffered LDS with 1 barrier/tile, source-swizzled
// global_load_lds staging, bijective XCD swizzle, nontemporal E traffic.

#define B_ 16
#define S_ 2048
#define D_ 256
#define SCALE_ 0.0625f

typedef __attribute__((ext_vector_type(8))) short bf16x8;
typedef __attribute__((ext_vector_type(4))) float f32x4;

__device__ __forceinline__ uint16_t f2bf(float f) {
  uint32_t u = __float_as_uint(f);
  u += 0x7fffu + ((u >> 16) & 1u);  // RNE
  return (uint16_t)(u >> 16);
}

typedef __attribute__((address_space(3))) uint32_t lds_u32;
typedef __attribute__((address_space(1))) const uint32_t glb_u32;
__device__ __forceinline__ void gload_lds16(const void* g, void* l) {
  // 16B direct global->LDS; LDS dest is wave-uniform base + lane*16.
  __builtin_amdgcn_global_load_lds((glb_u32*)g, (lds_u32*)l, 16, 0, 0);
}

// ---------------- K -> bf16 ----------------
__global__ void k_convert(const float* __restrict__ src, uint16_t* __restrict__ dst) {
  const int t = blockIdx.x * blockDim.x + threadIdx.x;  // 8 elems/thread
  const float4* s = (const float4*)src + (size_t)t * 2;
  float4 a = s[0], b = s[1];
  ushort4 lo = { f2bf(a.x), f2bf(a.y), f2bf(a.z), f2bf(a.w) };
  ushort4 hi = { f2bf(b.x), f2bf(b.y), f2bf(b.z), f2bf(b.w) };
  ((ushort4*)dst)[(size_t)t * 2]     = lo;
  ((ushort4*)dst)[(size_t)t * 2 + 1] = hi;
}

// ---------------- V -> V^T bf16 ----------------
__global__ void k_transpose(const float* __restrict__ V, uint16_t* __restrict__ Vt) {
  __shared__ float tile[64][68];
  const int b = blockIdx.z, kv0 = blockIdx.x * 64, d0 = blockIdx.y * 64;
  const int t = threadIdx.x;
  {
    const int r = t >> 2, c = (t & 3) * 16;
    const float4* src = (const float4*)(V + ((size_t)b * S_ + kv0 + r) * D_ + d0 + c);
    float4 x0 = src[0], x1 = src[1], x2 = src[2], x3 = src[3];
    *(float4*)&tile[r][c]      = x0;
    *(float4*)&tile[r][c + 4]  = x1;
    *(float4*)&tile[r][c + 8]  = x2;
    *(float4*)&tile[r][c + 12] = x3;
  }
  __syncthreads();
  {
    const int dl = t >> 2, c = (t & 3) * 16;
    uint16_t o[16];
#pragma unroll
    for (int i = 0; i < 16; ++i) o[i] = f2bf(tile[c + i][dl]);
    uint16_t* dst = Vt + ((size_t)b * D_ + d0 + dl) * S_ + kv0 + c;
#pragma unroll
    for (int i = 0; i < 4; ++i) {
      ushort4 v4 = { o[4*i], o[4*i+1], o[4*i+2], o[4*i+3] };
      *(ushort4*)(dst + 4*i) = v4;
    }
  }
}

// ---------------- mask -> bit-packed u64 per (row, 64-kv chunk) ----------------
__global__ void k_maskpack(const int* __restrict__ mask, unsigned long long* __restrict__ Mb) {
  const int wid  = blockIdx.x * 4 + (threadIdx.x >> 6);
  const int lane = threadIdx.x & 63;
  const int row = wid >> 5, w64 = wid & 31;
  const int m = mask[(size_t)row * S_ + w64 * 64 + lane];
  unsigned long long bits = __ballot(m != 0);
  if (lane == 0) Mb[row * 32 + w64] = bits;
}

// ---------------- scores: E = exp(masked s) (unnormalized), Winv = 1/rowsum --
__global__ __launch_bounds__(512, 4) void k_attn(
    const float* __restrict__ Q, const uint16_t* __restrict__ Kb,
    const unsigned long long* __restrict__ Mb,
    float* __restrict__ E, float* __restrict__ Winv) {
  __shared__ uint16_t Ks[2][64 * 256];  // 2 x 32 KB, source-swizzled, linear dest
  const int bid = blockIdx.x;           // 0..511
  const int swz = (bid & 7) * 64 + (bid >> 3);  // XCD i -> batches 2i,2i+1
  const int b = swz >> 5, q0 = (swz & 31) * 64;
  const int tid = threadIdx.x, w = tid >> 6, lane = tid & 63;
  const int wq = w >> 1, wkv = w & 1;   // 8 waves: 4 q-groups x 2 kv-halves
  const int l15 = lane & 15, lq = lane >> 4;
  const int qbase = q0 + wq * 16;       // wave owns 16 q-rows x 32 kv

  // Q fragments in VGPRs: 1 q-subtile x 8 d-chunks
  bf16x8 aq[8];
  {
    const float* qrow = Q + ((size_t)b * S_ + qbase + l15) * D_;
#pragma unroll
    for (int dc = 0; dc < 8; ++dc) {
      const float4* p = (const float4*)(qrow + dc * 32 + lq * 8);
      float4 x = p[0], y = p[1];
      union { bf16x8 v; uint16_t u[8]; } fr;
      fr.u[0] = f2bf(x.x); fr.u[1] = f2bf(x.y); fr.u[2] = f2bf(x.z); fr.u[3] = f2bf(x.w);
      fr.u[4] = f2bf(y.x); fr.u[5] = f2bf(y.y); fr.u[6] = f2bf(y.z); fr.u[7] = f2bf(y.w);
      aq[dc] = fr.v;
    }
  }

  float rowpart[4] = {0.f, 0.f, 0.f, 0.f};

  // stage K tile t (64 kv x 256 d bf16) into Ks[t&1]; swizzled source, linear LDS.
  auto stage = [&](int t) {
    const uint16_t* tbase = Kb + ((size_t)b * S_ + t * 64) * D_;
    uint16_t* lbase = Ks[t & 1];
#pragma unroll
    for (int it = 0; it < 4; ++it) {
      const int s = (it * 8 + w) * 64 + lane;  // 16B-granule index 0..2047
      const int r = s >> 5, c = s & 31;
      const int g = (c & ~7) | ((c ^ r) & 7);
      gload_lds16(tbase + (size_t)r * D_ + g * 8, lbase + (size_t)(it * 8 + w) * 64 * 8);
    }
  };

  stage(0);  // prologue

  for (int t = 0; t < 32; ++t) {
    __syncthreads();              // Ks[t&1] loads drained; prev-tile reads done
    if (t + 1 < 32) stage(t + 1); // overlap next staging with this compute
    const uint16_t* kbuf = Ks[t & 1];

    f32x4 acc[2];
    acc[0] = 0.f; acc[1] = 0.f;

#pragma unroll
    for (int dc = 0; dc < 8; ++dc) {
      bf16x8 bk[2];
#pragma unroll
      for (int kt = 0; kt < 2; ++kt) {
        const int kvl = wkv * 32 + kt * 16 + l15;
        const int g = dc * 4 + lq;
        const int gs = (g & ~7) | ((g ^ kvl) & 7);
        bk[kt] = *(const bf16x8*)&kbuf[(kvl * 32 + gs) * 8];
      }
      __builtin_amdgcn_s_setprio(1);
#pragma unroll
      for (int kt = 0; kt < 2; ++kt)
        acc[kt] = __builtin_amdgcn_mfma_f32_16x16x32_bf16(
            aq[dc], bk[kt], acc[kt], 0, 0, 0);
      __builtin_amdgcn_s_setprio(0);
    }

    // epilogue: mask+exp, nontemporal E store, rowsum accumulate
    const int kvb = t * 64;
#pragma unroll
    for (int r = 0; r < 4; ++r) {
      const int row = qbase + lq * 4 + r;
      const unsigned long long mw = Mb[(size_t)row * 32 + t];
      float* erow = E + (size_t)b * S_ * S_ + (size_t)row * S_ + kvb + wkv * 32 + l15;
#pragma unroll
      for (int kt = 0; kt < 2; ++kt) {
        const float sc = acc[kt][r] * SCALE_;
        const int bit = wkv * 32 + kt * 16 + l15;
        const float e = ((mw >> bit) & 1ull) ? __expf(sc) : 0.0f;
        rowpart[r] += e;
        __builtin_nontemporal_store(e, erow + kt * 16);
      }
    }
  }

  // rowsum: 16-lane shfl reduce, combine wkv halves via LDS (reuse Ks[0])
#pragma unroll
  for (int r = 0; r < 4; ++r) {
    float vs = rowpart[r];
    vs += __shfl_xor(vs, 1); vs += __shfl_xor(vs, 2);
    vs += __shfl_xor(vs, 4); vs += __shfl_xor(vs, 8);
    rowpart[r] = vs;
  }
  float* red = (float*)(void*)Ks[0];
  if (l15 == 0) {
#pragma unroll
    for (int r = 0; r < 4; ++r)
      red[wkv * 64 + wq * 16 + lq * 4 + r] = rowpart[r];
  }
  __syncthreads();
  if (wkv == 0 && l15 == 0) {
#pragma unroll
    for (int r = 0; r < 4; ++r) {
      const int rl = wq * 16 + lq * 4 + r;
      Winv[(size_t)b * S_ + q0 + rl] = 1.0f / (red[rl] + red[64 + rl]);
    }
  }
}

// ---------------- O = (E*inv) @ V; writes normalized attn in-place ----------
__global__ __launch_bounds__(512, 4) void k_out(
    float* __restrict__ attn, const uint16_t* __restrict__ Vt,
    const float* __restrict__ Winv, float* __restrict__ O) {
  __shared__ uint16_t As[2][64 * 64];    // 2 x 8 KB, XOR-swizzled [q][kv]
  __shared__ uint16_t Vs[2][256 * 64];   // 2 x 32 KB, source-swizzled [d][kv]
  const int bid = blockIdx.x;
  const int swz = (bid & 7) * 64 + (bid >> 3);
  const int b = swz >> 5, q0 = (swz & 31) * 64;
  const int tid = threadIdx.x, w = tid >> 6, lane = tid & 63;  // w = d-group 0..7
  const int l15 = lane & 15, lq = lane >> 4;
  const int srow = tid >> 3;            // 0..63
  const int scol = (tid & 7) * 8;       // 0..56, 8 floats per thread
  const float inv_r = Winv[(size_t)b * S_ + q0 + srow];
  float* aprow = attn + ((size_t)b * S_ + q0 + srow) * S_ + scol;

  f32x4 acc[4][2];
#pragma unroll
  for (int qt = 0; qt < 4; ++qt)
#pragma unroll
    for (int dt = 0; dt < 2; ++dt) acc[qt][dt] = 0.f;

  f32x4 e0, e1;

  auto stageV = [&](int t) {
    const uint16_t* tbase = Vt + (size_t)b * D_ * S_ + t * 64;
    uint16_t* lbase = Vs[t & 1];
#pragma unroll
    for (int it = 0; it < 4; ++it) {
      const int s = (it * 8 + w) * 64 + lane;  // granule 0..2047
      const int d = s >> 3, c = s & 7;
      const int g = c ^ (d & 7);
      gload_lds16(tbase + (size_t)d * S_ + g * 8, lbase + (size_t)(it * 8 + w) * 64 * 8);
    }
  };
  auto loadE = [&](int t) {
    const f32x4* ap = (const f32x4*)(aprow + (size_t)t * 64);
    e0 = __builtin_nontemporal_load(ap);
    e1 = __builtin_nontemporal_load(ap + 1);
  };
  auto procE = [&](int t) {
    e0 *= inv_r; e1 *= inv_r;
    f32x4* ap = (f32x4*)(aprow + (size_t)t * 64);
    __builtin_nontemporal_store(e0, ap);
    __builtin_nontemporal_store(e1, ap + 1);
    union { uint4 u; uint16_t h[8]; } g0;
    g0.h[0] = f2bf(e0[0]); g0.h[1] = f2bf(e0[1]); g0.h[2] = f2bf(e0[2]); g0.h[3] = f2bf(e0[3]);
    g0.h[4] = f2bf(e1[0]); g0.h[5] = f2bf(e1[1]); g0.h[6] = f2bf(e1[2]); g0.h[7] = f2bf(e1[3]);
    const int gc = tid & 7;
    uint16_t* abuf = As[t & 1];
    *(uint4*)&abuf[(srow * 8 + (gc ^ (srow & 7))) * 8] = g0.u;
  };

  // prologue
  stageV(0);
  loadE(0);
  procE(0);

  for (int t = 0; t < 32; ++t) {
    __syncthreads();  // Vs[t&1] drained; As[t&1] visible; prev reads done
    if (t + 1 < 32) { stageV(t + 1); loadE(t + 1); }
    const uint16_t* abuf = As[t & 1];
    const uint16_t* vbuf = Vs[t & 1];

#pragma unroll
    for (int kc = 0; kc < 2; ++kc) {
      bf16x8 af[4], bv[2];
      const int g = kc * 4 + lq;
#pragma unroll
      for (int qt = 0; qt < 4; ++qt) {
        const int ql = qt * 16 + l15;
        af[qt] = *(const bf16x8*)&abuf[(ql * 8 + (g ^ (ql & 7))) * 8];
      }
#pragma unroll
      for (int dt = 0; dt < 2; ++dt) {
        const int dl = w * 32 + dt * 16 + l15;
        bv[dt] = *(const bf16x8*)&vbuf[(dl * 8 + (g ^ (dl & 7))) * 8];
      }
      __builtin_amdgcn_s_setprio(1);
#pragma unroll
      for (int qt = 0; qt < 4; ++qt)
#pragma unroll
        for (int dt = 0; dt < 2; ++dt)
          acc[qt][dt] = __builtin_amdgcn_mfma_f32_16x16x32_bf16(af[qt], bv[dt], acc[qt][dt], 0, 0, 0);
      __builtin_amdgcn_s_setprio(0);
    }
    if (t + 1 < 32) procE(t + 1);  // E regs ready by now; writes next-parity As
  }

#pragma unroll
  for (int qt = 0; qt < 4; ++qt)
#pragma unroll
    for (int dt = 0; dt < 2; ++dt)
#pragma unroll
      for (int r = 0; r < 4; ++r)
        O[((size_t)b * S_ + q0 + qt * 16 + lq * 4 + r) * D_ +
          w * 32 + dt * 16 + l15] = acc[qt][dt][r];
}

extern "C" void kernel_launch(void* const* d_in, const int* in_sizes, int n_in,
                              void* d_out, int out_size, void* d_ws, size_t ws_size,
                              hipStream_t stream) {
  const float* q = (const float*)d_in[0];
  const float* k = (const float*)d_in[1];
  const float* v = (const float*)d_in[2];
  const int* mask = (const int*)d_in[3];

  float* out  = (float*)d_out;
  float* attn = out + (size_t)B_ * S_ * D_;

  uint16_t* Kb = (uint16_t*)d_ws;                                   // 16.78 MB
  uint16_t* Vt = Kb + (size_t)B_ * S_ * D_;                         // 16.78 MB
  unsigned long long* Mb = (unsigned long long*)(Vt + (size_t)B_ * S_ * D_);  // 0.5 MB
  float* Winv = (float*)(Mb + (size_t)S_ * 32);                     // 128 KB
  // total ws: ~34.2 MB

  k_convert<<<dim3(2048), dim3(512), 0, stream>>>(k, Kb);
  k_transpose<<<dim3(32, 4, 16), dim3(256), 0, stream>>>(v, Vt);
  k_maskpack<<<dim3(16384), dim3(256), 0, stream>>>(mask, Mb);
  k_attn<<<dim3(512), dim3(512), 0, stream>>>(q, Kb, Mb, attn, Winv);
  k_out<<<dim3(512), dim3(512), 0, stream>>>(attn, Vt, Winv, out);
}

// Round 6
// 569.458 us; speedup vs baseline: 1.2106x; 1.2106x over previous
//
#include <hip/hip_runtime.h>
#include <hip/hip_bf16.h>
#include <stdint.h>

// DenseAttention: B=16, S=2048, D=256, fp32 in/out.
// d_out = [output (16*2048*256) | attn_weights (16*2048*2048)] fp32.
// Round 6: NT removed everywhere (R5 post-mortem: NT scalar stores caused 2x
// write amplification + L2 thrash). k_attn = R4 256-thr shape, plain stores.
// k_out = R5 512-thr dbuf shape, plain loads/stores. Both: dbuf LDS with
// 1 barrier/tile, source-swizzled global_load_lds, bijective XCD swizzle.

#define B_ 16
#define S_ 2048
#define D_ 256
#define SCALE_ 0.0625f

typedef __attribute__((ext_vector_type(8))) short bf16x8;
typedef __attribute__((ext_vector_type(4))) float f32x4;

__device__ __forceinline__ uint16_t f2bf(float f) {
  uint32_t u = __float_as_uint(f);
  u += 0x7fffu + ((u >> 16) & 1u);  // RNE
  return (uint16_t)(u >> 16);
}

typedef __attribute__((address_space(3))) uint32_t lds_u32;
typedef __attribute__((address_space(1))) const uint32_t glb_u32;
__device__ __forceinline__ void gload_lds16(const void* g, void* l) {
  // 16B direct global->LDS; LDS dest is wave-uniform base + lane*16.
  __builtin_amdgcn_global_load_lds((glb_u32*)g, (lds_u32*)l, 16, 0, 0);
}

// ---------------- K -> bf16 ----------------
__global__ void k_convert(const float* __restrict__ src, uint16_t* __restrict__ dst) {
  const int t = blockIdx.x * blockDim.x + threadIdx.x;  // 8 elems/thread
  const float4* s = (const float4*)src + (size_t)t * 2;
  float4 a = s[0], b = s[1];
  ushort4 lo = { f2bf(a.x), f2bf(a.y), f2bf(a.z), f2bf(a.w) };
  ushort4 hi = { f2bf(b.x), f2bf(b.y), f2bf(b.z), f2bf(b.w) };
  ((ushort4*)dst)[(size_t)t * 2]     = lo;
  ((ushort4*)dst)[(size_t)t * 2 + 1] = hi;
}

// ---------------- V -> V^T bf16 ----------------
__global__ void k_transpose(const float* __restrict__ V, uint16_t* __restrict__ Vt) {
  __shared__ float tile[64][68];
  const int b = blockIdx.z, kv0 = blockIdx.x * 64, d0 = blockIdx.y * 64;
  const int t = threadIdx.x;
  {
    const int r = t >> 2, c = (t & 3) * 16;
    const float4* src = (const float4*)(V + ((size_t)b * S_ + kv0 + r) * D_ + d0 + c);
    float4 x0 = src[0], x1 = src[1], x2 = src[2], x3 = src[3];
    *(float4*)&tile[r][c]      = x0;
    *(float4*)&tile[r][c + 4]  = x1;
    *(float4*)&tile[r][c + 8]  = x2;
    *(float4*)&tile[r][c + 12] = x3;
  }
  __syncthreads();
  {
    const int dl = t >> 2, c = (t & 3) * 16;
    uint16_t o[16];
#pragma unroll
    for (int i = 0; i < 16; ++i) o[i] = f2bf(tile[c + i][dl]);
    uint16_t* dst = Vt + ((size_t)b * D_ + d0 + dl) * S_ + kv0 + c;
#pragma unroll
    for (int i = 0; i < 4; ++i) {
      ushort4 v4 = { o[4*i], o[4*i+1], o[4*i+2], o[4*i+3] };
      *(ushort4*)(dst + 4*i) = v4;
    }
  }
}

// ---------------- mask -> bit-packed u64 per (row, 64-kv chunk) ----------------
__global__ void k_maskpack(const int* __restrict__ mask, unsigned long long* __restrict__ Mb) {
  const int wid  = blockIdx.x * 4 + (threadIdx.x >> 6);
  const int lane = threadIdx.x & 63;
  const int row = wid >> 5, w64 = wid & 31;
  const int m = mask[(size_t)row * S_ + w64 * 64 + lane];
  unsigned long long bits = __ballot(m != 0);
  if (lane == 0) Mb[row * 32 + w64] = bits;
}

// ---------------- scores: E = exp(masked s) (unnormalized), Winv = 1/rowsum --
__global__ __launch_bounds__(256, 2) void k_attn(
    const float* __restrict__ Q, const uint16_t* __restrict__ Kb,
    const unsigned long long* __restrict__ Mb,
    float* __restrict__ E, float* __restrict__ Winv) {
  __shared__ uint16_t Ks[2][64 * 256];  // 2 x 32 KB, source-swizzled, linear dest
  const int bid = blockIdx.x;           // 0..511
  const int swz = (bid & 7) * 64 + (bid >> 3);  // XCD i -> batches 2i,2i+1
  const int b = swz >> 5, q0 = (swz & 31) * 64;
  const int tid = threadIdx.x, w = tid >> 6, lane = tid & 63;
  const int wq = w >> 1, wkv = w & 1;   // wave: 32q x 32kv
  const int l15 = lane & 15, lq = lane >> 4;
  const int qbase = q0 + wq * 32;

  // Q fragments in VGPRs: 2 q-subtiles x 8 d-chunks
  bf16x8 aq[2][8];
#pragma unroll
  for (int qt = 0; qt < 2; ++qt) {
    const float* qrow = Q + ((size_t)b * S_ + qbase + qt * 16 + l15) * D_;
#pragma unroll
    for (int dc = 0; dc < 8; ++dc) {
      const float4* p = (const float4*)(qrow + dc * 32 + lq * 8);
      float4 x = p[0], y = p[1];
      union { bf16x8 v; uint16_t u[8]; } fr;
      fr.u[0] = f2bf(x.x); fr.u[1] = f2bf(x.y); fr.u[2] = f2bf(x.z); fr.u[3] = f2bf(x.w);
      fr.u[4] = f2bf(y.x); fr.u[5] = f2bf(y.y); fr.u[6] = f2bf(y.z); fr.u[7] = f2bf(y.w);
      aq[qt][dc] = fr.v;
    }
  }

  float rowpart[2][4] = {{0.f,0.f,0.f,0.f},{0.f,0.f,0.f,0.f}};

  // stage K tile t (64 kv x 256 d bf16) into Ks[t&1]; swizzled source, linear LDS.
  auto stage = [&](int t) {
    const uint16_t* tbase = Kb + ((size_t)b * S_ + t * 64) * D_;
    uint16_t* lbase = Ks[t & 1];
#pragma unroll
    for (int it = 0; it < 8; ++it) {
      const int s = (it * 4 + w) * 64 + lane;  // 16B-granule index 0..2047
      const int r = s >> 5, c = s & 31;
      const int g = (c & ~7) | ((c ^ r) & 7);
      gload_lds16(tbase + (size_t)r * D_ + g * 8, lbase + (size_t)(it * 4 + w) * 64 * 8);
    }
  };

  stage(0);  // prologue

  for (int t = 0; t < 32; ++t) {
    __syncthreads();              // Ks[t&1] loads drained; prev-tile reads done
    if (t + 1 < 32) stage(t + 1); // overlap next staging with this compute
    const uint16_t* kbuf = Ks[t & 1];

    f32x4 acc[2][2];
#pragma unroll
    for (int qt = 0; qt < 2; ++qt)
#pragma unroll
      for (int kt = 0; kt < 2; ++kt) acc[qt][kt] = 0.f;

#pragma unroll
    for (int dc = 0; dc < 8; ++dc) {
      bf16x8 bk[2];
#pragma unroll
      for (int kt = 0; kt < 2; ++kt) {
        const int kvl = wkv * 32 + kt * 16 + l15;
        const int g = dc * 4 + lq;
        const int gs = (g & ~7) | ((g ^ kvl) & 7);
        bk[kt] = *(const bf16x8*)&kbuf[(kvl * 32 + gs) * 8];
      }
      __builtin_amdgcn_s_setprio(1);
#pragma unroll
      for (int qt = 0; qt < 2; ++qt)
#pragma unroll
        for (int kt = 0; kt < 2; ++kt)
          acc[qt][kt] = __builtin_amdgcn_mfma_f32_16x16x32_bf16(
              aq[qt][dc], bk[kt], acc[qt][kt], 0, 0, 0);
      __builtin_amdgcn_s_setprio(0);
    }

    // epilogue: mask+exp, plain E store, rowsum accumulate
    const int kvb = t * 64;
#pragma unroll
    for (int qt = 0; qt < 2; ++qt) {
#pragma unroll
      for (int r = 0; r < 4; ++r) {
        const int row = qbase + qt * 16 + lq * 4 + r;
        const unsigned long long mw = Mb[(size_t)row * 32 + t];
        float* erow = E + (size_t)b * S_ * S_ + (size_t)row * S_ + kvb + wkv * 32 + l15;
#pragma unroll
        for (int kt = 0; kt < 2; ++kt) {
          const float sc = acc[qt][kt][r] * SCALE_;
          const int bit = wkv * 32 + kt * 16 + l15;
          const float e = ((mw >> bit) & 1ull) ? __expf(sc) : 0.0f;
          rowpart[qt][r] += e;
          erow[kt * 16] = e;
        }
      }
    }
  }

  // rowsum: 16-lane shfl reduce, combine wkv halves via LDS (reuse Ks[0])
#pragma unroll
  for (int qt = 0; qt < 2; ++qt)
#pragma unroll
    for (int r = 0; r < 4; ++r) {
      float vs = rowpart[qt][r];
      vs += __shfl_xor(vs, 1); vs += __shfl_xor(vs, 2);
      vs += __shfl_xor(vs, 4); vs += __shfl_xor(vs, 8);
      rowpart[qt][r] = vs;
    }
  __syncthreads();
  float* red = (float*)(void*)Ks[0];
  if (l15 == 0) {
#pragma unroll
    for (int qt = 0; qt < 2; ++qt)
#pragma unroll
      for (int r = 0; r < 4; ++r)
        red[wkv * 64 + wq * 32 + qt * 16 + lq * 4 + r] = rowpart[qt][r];
  }
  __syncthreads();
  if (wkv == 0 && l15 == 0) {
#pragma unroll
    for (int qt = 0; qt < 2; ++qt)
#pragma unroll
      for (int r = 0; r < 4; ++r) {
        const int rl = wq * 32 + qt * 16 + lq * 4 + r;
        Winv[(size_t)b * S_ + q0 + rl] = 1.0f / (red[rl] + red[64 + rl]);
      }
  }
}

// ---------------- O = (E*inv) @ V; writes normalized attn in-place ----------
__global__ __launch_bounds__(512, 4) void k_out(
    float* __restrict__ attn, const uint16_t* __restrict__ Vt,
    const float* __restrict__ Winv, float* __restrict__ O) {
  __shared__ uint16_t As[2][64 * 64];    // 2 x 8 KB, XOR-swizzled [q][kv]
  __shared__ uint16_t Vs[2][256 * 64];   // 2 x 32 KB, source-swizzled [d][kv]
  const int bid = blockIdx.x;
  const int swz = (bid & 7) * 64 + (bid >> 3);
  const int b = swz >> 5, q0 = (swz & 31) * 64;
  const int tid = threadIdx.x, w = tid >> 6, lane = tid & 63;  // w = d-group 0..7
  const int l15 = lane & 15, lq = lane >> 4;
  const int srow = tid >> 3;            // 0..63
  const int scol = (tid & 7) * 8;       // 0..56, 8 floats per thread
  const float inv_r = Winv[(size_t)b * S_ + q0 + srow];
  float* aprow = attn + ((size_t)b * S_ + q0 + srow) * S_ + scol;

  f32x4 acc[4][2];
#pragma unroll
  for (int qt = 0; qt < 4; ++qt)
#pragma unroll
    for (int dt = 0; dt < 2; ++dt) acc[qt][dt] = 0.f;

  f32x4 e0, e1;

  auto stageV = [&](int t) {
    const uint16_t* tbase = Vt + (size_t)b * D_ * S_ + t * 64;
    uint16_t* lbase = Vs[t & 1];
#pragma unroll
    for (int it = 0; it < 4; ++it) {
      const int s = (it * 8 + w) * 64 + lane;  // granule 0..2047
      const int d = s >> 3, c = s & 7;
      const int g = c ^ (d & 7);
      gload_lds16(tbase + (size_t)d * S_ + g * 8, lbase + (size_t)(it * 8 + w) * 64 * 8);
    }
  };
  auto loadE = [&](int t) {
    const f32x4* ap = (const f32x4*)(aprow + (size_t)t * 64);
    e0 = ap[0];
    e1 = ap[1];
  };
  auto procE = [&](int t) {
    e0 *= inv_r; e1 *= inv_r;
    f32x4* ap = (f32x4*)(aprow + (size_t)t * 64);
    ap[0] = e0;
    ap[1] = e1;
    union { uint4 u; uint16_t h[8]; } g0;
    g0.h[0] = f2bf(e0[0]); g0.h[1] = f2bf(e0[1]); g0.h[2] = f2bf(e0[2]); g0.h[3] = f2bf(e0[3]);
    g0.h[4] = f2bf(e1[0]); g0.h[5] = f2bf(e1[1]); g0.h[6] = f2bf(e1[2]); g0.h[7] = f2bf(e1[3]);
    const int gc = tid & 7;
    uint16_t* abuf = As[t & 1];
    *(uint4*)&abuf[(srow * 8 + (gc ^ (srow & 7))) * 8] = g0.u;
  };

  // prologue
  stageV(0);
  loadE(0);
  procE(0);

  for (int t = 0; t < 32; ++t) {
    __syncthreads();  // Vs[t&1] drained; As[t&1] visible; prev reads done
    if (t + 1 < 32) { stageV(t + 1); loadE(t + 1); }
    const uint16_t* abuf = As[t & 1];
    const uint16_t* vbuf = Vs[t & 1];

#pragma unroll
    for (int kc = 0; kc < 2; ++kc) {
      bf16x8 af[4], bv[2];
      const int g = kc * 4 + lq;
#pragma unroll
      for (int qt = 0; qt < 4; ++qt) {
        const int ql = qt * 16 + l15;
        af[qt] = *(const bf16x8*)&abuf[(ql * 8 + (g ^ (ql & 7))) * 8];
      }
#pragma unroll
      for (int dt = 0; dt < 2; ++dt) {
        const int dl = w * 32 + dt * 16 + l15;
        bv[dt] = *(const bf16x8*)&vbuf[(dl * 8 + (g ^ (dl & 7))) * 8];
      }
      __builtin_amdgcn_s_setprio(1);
#pragma unroll
      for (int qt = 0; qt < 4; ++qt)
#pragma unroll
        for (int dt = 0; dt < 2; ++dt)
          acc[qt][dt] = __builtin_amdgcn_mfma_f32_16x16x32_bf16(af[qt], bv[dt], acc[qt][dt], 0, 0, 0);
      __builtin_amdgcn_s_setprio(0);
    }
    if (t + 1 < 32) procE(t + 1);  // E regs ready by now; writes next-parity As
  }

#pragma unroll
  for (int qt = 0; qt < 4; ++qt)
#pragma unroll
    for (int dt = 0; dt < 2; ++dt)
#pragma unroll
      for (int r = 0; r < 4; ++r)
        O[((size_t)b * S_ + q0 + qt * 16 + lq * 4 + r) * D_ +
          w * 32 + dt * 16 + l15] = acc[qt][dt][r];
}

extern "C" void kernel_launch(void* const* d_in, const int* in_sizes, int n_in,
                              void* d_out, int out_size, void* d_ws, size_t ws_size,
                              hipStream_t stream) {
  const float* q = (const float*)d_in[0];
  const float* k = (const float*)d_in[1];
  const float* v = (const float*)d_in[2];
  const int* mask = (const int*)d_in[3];

  float* out  = (float*)d_out;
  float* attn = out + (size_t)B_ * S_ * D_;

  uint16_t* Kb = (uint16_t*)d_ws;                                   // 16.78 MB
  uint16_t* Vt = Kb + (size_t)B_ * S_ * D_;                         // 16.78 MB
  unsigned long long* Mb = (unsigned long long*)(Vt + (size_t)B_ * S_ * D_);  // 0.5 MB
  float* Winv = (float*)(Mb + (size_t)S_ * 32);                     // 128 KB
  // total ws: ~34.2 MB

  k_convert<<<dim3(2048), dim3(512), 0, stream>>>(k, Kb);
  k_transpose<<<dim3(32, 4, 16), dim3(256), 0, stream>>>(v, Vt);
  k_maskpack<<<dim3(16384), dim3(256), 0, stream>>>(mask, Mb);
  k_attn<<<dim3(512), dim3(256), 0, stream>>>(q, Kb, Mb, attn, Winv);
  k_out<<<dim3(512), dim3(512), 0, stream>>>(attn, Vt, Winv, out);
}

// Round 7
// 567.027 us; speedup vs baseline: 1.2158x; 1.0043x over previous
//
#include <hip/hip_runtime.h>
#include <hip/hip_bf16.h>
#include <stdint.h>

// DenseAttention: B=16, S=2048, D=256, fp32 in/out.
// d_out = [output (16*2048*256) | attn_weights (16*2048*2048)] fp32.
// Round 7: bf16 E round-trip, staged INSIDE the attn slab (first half of each
// fp32 row holds the packed bf16 row). k_attn: E -> LDS tile -> coalesced 16B
// stores (134 MB instead of 268). k_out: reads bf16 E, feeds raw bf16 to PV
// (O scaled by inv at end), writes fp32 normalized attn; iterates kv tiles in
// REVERSE so the fp32 writes only clobber already-consumed bf16 tiles.
// Keeps: dbuf LDS 1 barrier/tile, source-swizzled global_load_lds, XCD swizzle.

#define B_ 16
#define S_ 2048
#define D_ 256
#define SCALE_ 0.0625f

typedef __attribute__((ext_vector_type(8))) short bf16x8;
typedef __attribute__((ext_vector_type(4))) float f32x4;

__device__ __forceinline__ uint16_t f2bf(float f) {
  uint32_t u = __float_as_uint(f);
  u += 0x7fffu + ((u >> 16) & 1u);  // RNE
  return (uint16_t)(u >> 16);
}

typedef __attribute__((address_space(3))) uint32_t lds_u32;
typedef __attribute__((address_space(1))) const uint32_t glb_u32;
__device__ __forceinline__ void gload_lds16(const void* g, void* l) {
  // 16B direct global->LDS; LDS dest is wave-uniform base + lane*16.
  __builtin_amdgcn_global_load_lds((glb_u32*)g, (lds_u32*)l, 16, 0, 0);
}

// ---------------- K -> bf16 ----------------
__global__ void k_convert(const float* __restrict__ src, uint16_t* __restrict__ dst) {
  const int t = blockIdx.x * blockDim.x + threadIdx.x;  // 8 elems/thread
  const float4* s = (const float4*)src + (size_t)t * 2;
  float4 a = s[0], b = s[1];
  ushort4 lo = { f2bf(a.x), f2bf(a.y), f2bf(a.z), f2bf(a.w) };
  ushort4 hi = { f2bf(b.x), f2bf(b.y), f2bf(b.z), f2bf(b.w) };
  ((ushort4*)dst)[(size_t)t * 2]     = lo;
  ((ushort4*)dst)[(size_t)t * 2 + 1] = hi;
}

// ---------------- V -> V^T bf16 ----------------
__global__ void k_transpose(const float* __restrict__ V, uint16_t* __restrict__ Vt) {
  __shared__ float tile[64][68];
  const int b = blockIdx.z, kv0 = blockIdx.x * 64, d0 = blockIdx.y * 64;
  const int t = threadIdx.x;
  {
    const int r = t >> 2, c = (t & 3) * 16;
    const float4* src = (const float4*)(V + ((size_t)b * S_ + kv0 + r) * D_ + d0 + c);
    float4 x0 = src[0], x1 = src[1], x2 = src[2], x3 = src[3];
    *(float4*)&tile[r][c]      = x0;
    *(float4*)&tile[r][c + 4]  = x1;
    *(float4*)&tile[r][c + 8]  = x2;
    *(float4*)&tile[r][c + 12] = x3;
  }
  __syncthreads();
  {
    const int dl = t >> 2, c = (t & 3) * 16;
    uint16_t o[16];
#pragma unroll
    for (int i = 0; i < 16; ++i) o[i] = f2bf(tile[c + i][dl]);
    uint16_t* dst = Vt + ((size_t)b * D_ + d0 + dl) * S_ + kv0 + c;
#pragma unroll
    for (int i = 0; i < 4; ++i) {
      ushort4 v4 = { o[4*i], o[4*i+1], o[4*i+2], o[4*i+3] };
      *(ushort4*)(dst + 4*i) = v4;
    }
  }
}

// ---------------- mask -> bit-packed u64 per (row, 64-kv chunk) ----------------
__global__ void k_maskpack(const int* __restrict__ mask, unsigned long long* __restrict__ Mb) {
  const int wid  = blockIdx.x * 4 + (threadIdx.x >> 6);
  const int lane = threadIdx.x & 63;
  const int row = wid >> 5, w64 = wid & 31;
  const int m = mask[(size_t)row * S_ + w64 * 64 + lane];
  unsigned long long bits = __ballot(m != 0);
  if (lane == 0) Mb[row * 32 + w64] = bits;
}

// ---------------- scores: Ebf (bf16, packed in attn rows), Winv = 1/rowsum ---
__global__ __launch_bounds__(256, 2) void k_attn(
    const float* __restrict__ Q, const uint16_t* __restrict__ Kb,
    const unsigned long long* __restrict__ Mb,
    uint16_t* __restrict__ Ebu, float* __restrict__ Winv) {
  __shared__ uint16_t Ks[2][64 * 256];  // 2 x 32 KB, source-swizzled, linear dest
  __shared__ uint16_t Et[2][64 * 64];   // 2 x 8 KB staging for coalesced E store
  const int bid = blockIdx.x;           // 0..511
  const int swz = (bid & 7) * 64 + (bid >> 3);  // XCD i -> batches 2i,2i+1
  const int b = swz >> 5, q0 = (swz & 31) * 64;
  const int tid = threadIdx.x, w = tid >> 6, lane = tid & 63;
  const int wq = w >> 1, wkv = w & 1;   // wave: 32q x 32kv
  const int l15 = lane & 15, lq = lane >> 4;
  const int qbase = q0 + wq * 32;

  // Q fragments in VGPRs: 2 q-subtiles x 8 d-chunks
  bf16x8 aq[2][8];
#pragma unroll
  for (int qt = 0; qt < 2; ++qt) {
    const float* qrow = Q + ((size_t)b * S_ + qbase + qt * 16 + l15) * D_;
#pragma unroll
    for (int dc = 0; dc < 8; ++dc) {
      const float4* p = (const float4*)(qrow + dc * 32 + lq * 8);
      float4 x = p[0], y = p[1];
      union { bf16x8 v; uint16_t u[8]; } fr;
      fr.u[0] = f2bf(x.x); fr.u[1] = f2bf(x.y); fr.u[2] = f2bf(x.z); fr.u[3] = f2bf(x.w);
      fr.u[4] = f2bf(y.x); fr.u[5] = f2bf(y.y); fr.u[6] = f2bf(y.z); fr.u[7] = f2bf(y.w);
      aq[qt][dc] = fr.v;
    }
  }

  float rowpart[2][4] = {{0.f,0.f,0.f,0.f},{0.f,0.f,0.f,0.f}};

  // stage K tile t (64 kv x 256 d bf16) into Ks[t&1]; swizzled source, linear LDS.
  auto stage = [&](int t) {
    const uint16_t* tbase = Kb + ((size_t)b * S_ + t * 64) * D_;
    uint16_t* lbase = Ks[t & 1];
#pragma unroll
    for (int it = 0; it < 8; ++it) {
      const int s = (it * 4 + w) * 64 + lane;  // 16B-granule index 0..2047
      const int r = s >> 5, c = s & 31;
      const int g = (c & ~7) | ((c ^ r) & 7);
      gload_lds16(tbase + (size_t)r * D_ + g * 8, lbase + (size_t)(it * 4 + w) * 64 * 8);
    }
  };

  // store Et[t&1] (64q x 64kv bf16) to global, coalesced 16B per thread.
  auto storeEt = [&](int t) {
    const uint16_t* src = Et[t & 1];
#pragma unroll
    for (int i = 0; i < 2; ++i) {
      const int c = i * 256 + tid;          // 0..511 chunks of 8 ushorts
      const int row = c >> 3, cg = c & 7;
      const bf16x8 vd = *(const bf16x8*)&src[row * 64 + cg * 8];
      *(bf16x8*)&Ebu[((size_t)b * S_ + q0 + row) * (size_t)S_ * 2 +
                     (size_t)t * 64 + cg * 8] = vd;
    }
  };

  stage(0);  // prologue

  for (int t = 0; t < 32; ++t) {
    __syncthreads();              // Ks[t&1] drained; Et[(t-1)&1] complete
    if (t + 1 < 32) stage(t + 1); // overlap next staging with this compute
    if (t > 0) storeEt(t - 1);    // coalesced store of previous E tile
    const uint16_t* kbuf = Ks[t & 1];

    f32x4 acc[2][2];
#pragma unroll
    for (int qt = 0; qt < 2; ++qt)
#pragma unroll
      for (int kt = 0; kt < 2; ++kt) acc[qt][kt] = 0.f;

#pragma unroll
    for (int dc = 0; dc < 8; ++dc) {
      bf16x8 bk[2];
#pragma unroll
      for (int kt = 0; kt < 2; ++kt) {
        const int kvl = wkv * 32 + kt * 16 + l15;
        const int g = dc * 4 + lq;
        const int gs = (g & ~7) | ((g ^ kvl) & 7);
        bk[kt] = *(const bf16x8*)&kbuf[(kvl * 32 + gs) * 8];
      }
      __builtin_amdgcn_s_setprio(1);
#pragma unroll
      for (int qt = 0; qt < 2; ++qt)
#pragma unroll
        for (int kt = 0; kt < 2; ++kt)
          acc[qt][kt] = __builtin_amdgcn_mfma_f32_16x16x32_bf16(
              aq[qt][dc], bk[kt], acc[qt][kt], 0, 0, 0);
      __builtin_amdgcn_s_setprio(0);
    }

    // epilogue: mask+exp -> bf16, LDS tile write, rowsum over ROUNDED values
#pragma unroll
    for (int qt = 0; qt < 2; ++qt) {
#pragma unroll
      for (int r = 0; r < 4; ++r) {
        const int qloc = wq * 32 + qt * 16 + lq * 4 + r;
        const int row = q0 + qloc;
        const unsigned long long mw = Mb[(size_t)row * 32 + t];
#pragma unroll
        for (int kt = 0; kt < 2; ++kt) {
          const float sc = acc[qt][kt][r] * SCALE_;
          const int bit = wkv * 32 + kt * 16 + l15;
          uint16_t eb = 0;
          if ((mw >> bit) & 1ull) eb = f2bf(__expf(sc));
          rowpart[qt][r] += __uint_as_float((uint32_t)eb << 16);
          Et[t & 1][qloc * 64 + wkv * 32 + kt * 16 + l15] = eb;
        }
      }
    }
  }

  __syncthreads();   // Et[31&1] complete; all Ks reads done
  storeEt(31);

  // rowsum: 16-lane shfl reduce, combine wkv halves via LDS (reuse Ks[0])
#pragma unroll
  for (int qt = 0; qt < 2; ++qt)
#pragma unroll
    for (int r = 0; r < 4; ++r) {
      float vs = rowpart[qt][r];
      vs += __shfl_xor(vs, 1); vs += __shfl_xor(vs, 2);
      vs += __shfl_xor(vs, 4); vs += __shfl_xor(vs, 8);
      rowpart[qt][r] = vs;
    }
  float* red = (float*)(void*)Ks[0];
  if (l15 == 0) {
#pragma unroll
    for (int qt = 0; qt < 2; ++qt)
#pragma unroll
      for (int r = 0; r < 4; ++r)
        red[wkv * 64 + wq * 32 + qt * 16 + lq * 4 + r] = rowpart[qt][r];
  }
  __syncthreads();
  if (wkv == 0 && l15 == 0) {
#pragma unroll
    for (int qt = 0; qt < 2; ++qt)
#pragma unroll
      for (int r = 0; r < 4; ++r) {
        const int rl = wq * 32 + qt * 16 + lq * 4 + r;
        Winv[(size_t)b * S_ + q0 + rl] = 1.0f / (red[rl] + red[64 + rl]);
      }
  }
}

// ------- O = (Ebf @ V) * inv; writes normalized fp32 attn (REVERSE kv order) -
__global__ __launch_bounds__(512, 4) void k_out(
    float* __restrict__ attn, const uint16_t* __restrict__ Vt,
    const float* __restrict__ Winv, float* __restrict__ O) {
  __shared__ uint16_t As[2][64 * 64];    // 2 x 8 KB, XOR-swizzled [q][kv]
  __shared__ uint16_t Vs[2][256 * 64];   // 2 x 32 KB, source-swizzled [d][kv]
  const int bid = blockIdx.x;
  const int swz = (bid & 7) * 64 + (bid >> 3);
  const int b = swz >> 5, q0 = (swz & 31) * 64;
  const int tid = threadIdx.x, w = tid >> 6, lane = tid & 63;  // w = d-group 0..7
  const int l15 = lane & 15, lq = lane >> 4;
  const int srow = tid >> 3;            // 0..63
  const int sc8 = (tid & 7) * 8;        // 8 elems per thread
  const float inv_r = Winv[(size_t)b * S_ + q0 + srow];
  const uint16_t* ebrow = (const uint16_t*)attn +
      ((size_t)b * S_ + q0 + srow) * (size_t)S_ * 2 + sc8;   // packed bf16 E
  float* aprow = attn + ((size_t)b * S_ + q0 + srow) * S_ + sc8;

  f32x4 acc[4][2];
#pragma unroll
  for (int qt = 0; qt < 4; ++qt)
#pragma unroll
    for (int dt = 0; dt < 2; ++dt) acc[qt][dt] = 0.f;

  union { uint4 u; uint16_t h[8]; } eu;

  auto stageV = [&](int t) {
    const uint16_t* tbase = Vt + (size_t)b * D_ * S_ + t * 64;
    uint16_t* lbase = Vs[t & 1];
#pragma unroll
    for (int it = 0; it < 4; ++it) {
      const int s = (it * 8 + w) * 64 + lane;  // granule 0..2047
      const int d = s >> 3, c = s & 7;
      const int g = c ^ (d & 7);
      gload_lds16(tbase + (size_t)d * S_ + g * 8, lbase + (size_t)(it * 8 + w) * 64 * 8);
    }
  };
  auto loadE = [&](int t) {
    eu.u = *(const uint4*)(ebrow + (size_t)t * 64);
  };
  auto procE = [&](int t) {
    // fp32 normalized attn write (destroys bf16 tiles 2t,2t+1: already read)
    f32x4 a0, a1;
#pragma unroll
    for (int j = 0; j < 4; ++j) {
      a0[j] = __uint_as_float((uint32_t)eu.h[j] << 16) * inv_r;
      a1[j] = __uint_as_float((uint32_t)eu.h[4 + j] << 16) * inv_r;
    }
    f32x4* ap = (f32x4*)(aprow + (size_t)t * 64);
    ap[0] = a0;
    ap[1] = a1;
    // raw (unnormalized) bf16 into swizzled As for PV
    const int gc = tid & 7;
    *(uint4*)&As[t & 1][(srow * 8 + (gc ^ (srow & 7))) * 8] = eu.u;
  };

  // prologue (reverse order: start at tile 31)
  stageV(31);
  loadE(31);
  procE(31);

  for (int t = 31; t >= 0; --t) {
    __syncthreads();  // Vs[t&1] drained; As[t&1] visible; prev reads done
    if (t > 0) { stageV(t - 1); loadE(t - 1); }
    const uint16_t* abuf = As[t & 1];
    const uint16_t* vbuf = Vs[t & 1];

#pragma unroll
    for (int kc = 0; kc < 2; ++kc) {
      bf16x8 af[4], bv[2];
      const int g = kc * 4 + lq;
#pragma unroll
      for (int qt = 0; qt < 4; ++qt) {
        const int ql = qt * 16 + l15;
        af[qt] = *(const bf16x8*)&abuf[(ql * 8 + (g ^ (ql & 7))) * 8];
      }
#pragma unroll
      for (int dt = 0; dt < 2; ++dt) {
        const int dl = w * 32 + dt * 16 + l15;
        bv[dt] = *(const bf16x8*)&vbuf[(dl * 8 + (g ^ (dl & 7))) * 8];
      }
      __builtin_amdgcn_s_setprio(1);
#pragma unroll
      for (int qt = 0; qt < 4; ++qt)
#pragma unroll
        for (int dt = 0; dt < 2; ++dt)
          acc[qt][dt] = __builtin_amdgcn_mfma_f32_16x16x32_bf16(af[qt], bv[dt], acc[qt][dt], 0, 0, 0);
      __builtin_amdgcn_s_setprio(0);
    }
    if (t > 0) procE(t - 1);  // E regs ready; writes next-parity As + attn
  }

  // O = acc * inv(row)
#pragma unroll
  for (int qt = 0; qt < 4; ++qt)
#pragma unroll
    for (int r = 0; r < 4; ++r) {
      const float invq = Winv[(size_t)b * S_ + q0 + qt * 16 + lq * 4 + r];
#pragma unroll
      for (int dt = 0; dt < 2; ++dt)
        O[((size_t)b * S_ + q0 + qt * 16 + lq * 4 + r) * D_ +
          w * 32 + dt * 16 + l15] = acc[qt][dt][r] * invq;
    }
}

extern "C" void kernel_launch(void* const* d_in, const int* in_sizes, int n_in,
                              void* d_out, int out_size, void* d_ws, size_t ws_size,
                              hipStream_t stream) {
  const float* q = (const float*)d_in[0];
  const float* k = (const float*)d_in[1];
  const float* v = (const float*)d_in[2];
  const int* mask = (const int*)d_in[3];

  float* out  = (float*)d_out;
  float* attn = out + (size_t)B_ * S_ * D_;

  uint16_t* Kb = (uint16_t*)d_ws;                                   // 16.78 MB
  uint16_t* Vt = Kb + (size_t)B_ * S_ * D_;                         // 16.78 MB
  unsigned long long* Mb = (unsigned long long*)(Vt + (size_t)B_ * S_ * D_);  // 0.5 MB
  float* Winv = (float*)(Mb + (size_t)S_ * 32);                     // 128 KB
  // total ws: ~34.2 MB

  k_convert<<<dim3(2048), dim3(512), 0, stream>>>(k, Kb);
  k_transpose<<<dim3(32, 4, 16), dim3(256), 0, stream>>>(v, Vt);
  k_maskpack<<<dim3(16384), dim3(256), 0, stream>>>(mask, Mb);
  k_attn<<<dim3(512), dim3(256), 0, stream>>>(q, Kb, Mb, (uint16_t*)attn, Winv);
  k_out<<<dim3(512), dim3(512), 0, stream>>>(attn, Vt, Winv, out);
}